// Round 13
// baseline (528.162 us; speedup 1.0000x reference)
//
#include <hip/hip_runtime.h>
#include <cstdint>
#include <cmath>

// Problem constants (from reference): T=512, N=32, C=5000, S=100
#define Tt   512
#define Nb   32
#define Cc   5000
#define Sm   100
#define NEGV (-1e30f)          // log-domain -inf surrogate (any base)
#define LOG2E 1.4426950408889634f
#define LN2   0.6931471805599453f

// Native 2^x / log2(x). __exp2f/__log2f do NOT exist device-side (glibc
// host decls caused round-9 compile failure); guarded builtins instead.
#if __has_builtin(__builtin_amdgcn_exp2f)
#define EXP2F(x) __builtin_amdgcn_exp2f(x)
#else
#define EXP2F(x) exp2f(x)
#endif
#if __has_builtin(__builtin_amdgcn_logf)
#define LOG2F(x) __builtin_amdgcn_logf(x)
#else
#define LOG2F(x) log2f(x)
#endif

// All lattice math in LOG2 domain (emissions pre-scaled by log2(e) in the
// gather; lse is scale-equivariant so alpha = log2(e) * alpha_nat exactly).
__device__ __forceinline__ float lse2_l2(float a, float b) {
    float m = fmaxf(a, b);
    return m + LOG2F(1.0f + EXP2F(fminf(a, b) - m));
}
__device__ __forceinline__ float lse3_l2(float a, float b, float c) {
    float m   = fmaxf(fmaxf(a, b), c);                 // v_max3
    float mid = __builtin_amdgcn_fmed3f(a, b, c);      // v_med3
    float lo  = fminf(fminf(a, b), c);                 // v_min3
    return m + LOG2F(1.0f + EXP2F(mid - m) + EXP2F(lo - m));
}

// ---------------------------------------------------------------------------
// Kernel 1 (ROUND-13 REWRITE — single-variable probe vs R12): coalesced-read
// + LDS-select gather. The old scattered gather issued ~1.6M isolated 4B
// reads (~104-208 MB of 64B lines at degraded random-access BW). Instead,
// each block stages the full 20KB lp[t][n][:] row via perfectly-coalesced
// float4 loads (327 MB total at ~6 TB/s ~= 55 us), then selects the 101
// needed columns from LDS. 16384 blocks; LDS 20.4 KB -> 7 blocks/CU.
// em2 layout identical to R12: [n][t][0..99]=labels, [100]=blank, pad=NEGV.
// ---------------------------------------------------------------------------
__global__ __launch_bounds__(256, 1)
void ctc_gather_kernel(const float* __restrict__ lp,    // [T,N,C]
                       const int*   __restrict__ tgt,   // [N,S]
                       float*       __restrict__ em2,   // [N,T,128] log2-dom
                       float*       __restrict__ out)   // [1] (init to 0)
{
    const int bid = blockIdx.x;          // = n*Tt + t
    const int n   = bid >> 9;            // Tt = 512
    const int t   = bid & (Tt - 1);
    const int tid = threadIdx.x;

    __shared__ float row[Cc];            // 20000 B
    __shared__ int   stgt[Sm];           // 400 B

    if (bid == 0 && tid == 255) out[0] = 0.0f;   // d_out re-poisoned each call

    // coalesced row stage: 5000 = 1250 float4, 256 threads x ~5
    const float4* src4 = (const float4*)(lp + ((size_t)t * Nb + n) * Cc);
#pragma unroll
    for (int idx = tid; idx < 1250; idx += 256) {
        float4 v = src4[idx];
        row[idx * 4 + 0] = v.x;
        row[idx * 4 + 1] = v.y;
        row[idx * 4 + 2] = v.z;
        row[idx * 4 + 3] = v.w;
    }
    if (tid < Sm) stgt[tid] = tgt[n * Sm + tid];
    __syncthreads();

    if (tid < 128) {                     // one coalesced 512B store
        float v;
        if (tid < Sm)       v = row[stgt[tid]] * LOG2E;   // label columns
        else if (tid == Sm) v = row[0] * LOG2E;           // blank column
        else                v = NEGV;                     // pad
        em2[((size_t)bid << 7) + tid] = v;
    }
}

// ---------------------------------------------------------------------------
// Kernel 2: alpha recursion — BYTE-IDENTICAL to round 12 (probe discipline).
// ONE WAVE per batch item, zero LDS/barriers, zero per-step memory ops
// beyond the prefetched float2 (blank = lane 50's e.x via v_readlane).
// Lane i owns cells 4i..4i+3; cross-lane need = cell 4i-1 via ds_bpermute.
// Finalize fused: per-block atomicAdd into out[0] (zeroed by gather).
// ---------------------------------------------------------------------------
__global__ __launch_bounds__(64, 1)
void ctc_alpha_wave_kernel(const float* __restrict__ em2,   // [N,T,128]
                           const int*   __restrict__ tgt,   // [N,S]
                           const int*   __restrict__ ilen,  // [N]
                           const int*   __restrict__ tlen,  // [N]
                           float*       __restrict__ out)   // [1] accum
{
    const int n = blockIdx.x;
    const int i = threadIdx.x;           // lane 0..63

    const int tl = tlen[n];
    const int il = ilen[n];

    // skip flags for odd cells 4i+1 (label j1=2i) and 4i+3 (label j3=2i+1)
    const int j1 = 2 * i, j3 = 2 * i + 1;
    bool s1 = false, s3 = false;
    if (j1 >= 1 && j1 < Sm) s1 = (tgt[n * Sm + j1] != tgt[n * Sm + j1 - 1]);
    if (j3 < Sm)            s3 = (tgt[n * Sm + j3] != tgt[n * Sm + j3 - 1]);

    const float2* e2 = (const float2*)em2 + ((size_t)n << 15);  // n*T*64

    // bpermute byte address for "value from lane i-1" (precomputed once)
    const int pull = (i > 0 ? i - 1 : 0) << 2;

    // ---- t = 0 init: only cells 0 and 1 live ----
    float2 E0 = e2[i];                   // lane 50 holds blank in E0.x
    float b0 = __int_as_float(
        __builtin_amdgcn_readlane(__float_as_int(E0.x), 50));
    float a0 = (i == 0)           ? b0   : NEGV;
    float a1 = (i == 0 && tl > 0) ? E0.x : NEGV;
    float a2 = NEGV;
    float a3 = NEGV;

    // ---- register prefetch: em2 float2 rows for t = 1..PF ----
    constexpr int PF = 8;
    float2 ebuf[PF];
#pragma unroll
    for (int k = 0; k < PF; ++k)         // t = 1..8, always < Tt
        ebuf[k] = e2[((1 + k) << 6) + i];

    for (int tb = 1; tb < Tt; tb += PF) {
#pragma unroll
        for (int k = 0; k < PF; ++k) {       // static ebuf index (rule #20)
            const int t = tb + k;
            if (t < Tt) {                    // block-uniform guard
                float2 e  = ebuf[k];
                int    tp = t + PF;
                if (tp < Tt) ebuf[k] = e2[(tp << 6) + i];   // prefetch

                // blank emission: lane 50's e.x, broadcast in-register
                float eb = __int_as_float(
                    __builtin_amdgcn_readlane(__float_as_int(e.x), 50));

                float p3  = __int_as_float(
                    __builtin_amdgcn_ds_bpermute(pull, __float_as_int(a3)));
                float am0 = (i > 0) ? p3 : NEGV;

                float n0 = lse2_l2(a0, am0)                   + eb;
                float n1 = lse3_l2(a1, a0, s1 ? p3 : NEGV)    + e.x;
                float n2 = lse2_l2(a2, a1)                    + eb;
                float n3 = lse3_l2(a3, a2, s3 ? a1 : NEGV)    + e.y;

                if (t < il) {                // freeze past input length
                    a0 = n0; a1 = n1; a2 = n2; a3 = n3;
                }
            }
        }
    }

    // ---- per-n loss: cells 2*tl and 2*tl-1 of final alpha (log2 -> nat) --
    const int lb = 2 * tl;
    const int lv = (lb - 1 >= 0) ? lb - 1 : 0;

    int   cb = lb & 3;
    float vb = (cb == 0) ? a0 : (cb == 1) ? a1 : (cb == 2) ? a2 : a3;
    float ab = __shfl(vb, lb >> 2);
    int   cl = lv & 3;
    float vl = (cl == 0) ? a0 : (cl == 1) ? a1 : (cl == 2) ? a2 : a3;
    float al = __shfl(vl, lv >> 2);

    if (i == 0) {
        float m    = fmaxf(ab, al);
        float ll2  = m + LOG2F(EXP2F(ab - m) + EXP2F(al - m));
        float loss = -ll2 * LN2;             // back to natural log
        if (!(isfinite(loss) && loss < 1e29f)) loss = 0.0f;  // zero_infinity
        int   d    = (tl >= 1) ? tl : 1;
        atomicAdd(out, loss / ((float)d * (float)Nb));  // fused mean
    }
}

extern "C" void kernel_launch(void* const* d_in, const int* in_sizes, int n_in,
                              void* d_out, int out_size, void* d_ws, size_t ws_size,
                              hipStream_t stream)
{
    const float* lp   = (const float*)d_in[0];   // [T,N,C] f32
    const int*   tgt  = (const int*)  d_in[1];   // [N,S]   i32
    const int*   ilen = (const int*)  d_in[2];   // [N]     i32
    const int*   tlen = (const int*)  d_in[3];   // [N]     i32
    float*       out  = (float*)d_out;           // scalar f32

    // ws layout: em2[N*T*128] (8.4 MB)
    float* em2 = (float*)d_ws;

    ctc_gather_kernel<<<Nb * Tt, 256, 0, stream>>>(lp, tgt, em2, out);
    ctc_alpha_wave_kernel<<<Nb, 64, 0, stream>>>(em2, tgt, ilen, tlen, out);
}